// Round 16
// baseline (2331.777 us; speedup 1.0000x reference)
//
#include <hip/hip_runtime.h>
#include <math.h>

#define BB  32
#define SQl 200
#define SKV 200
#define DD  1024
#define NH  16
#define HDm 64
#define NL  6
#define FFD 2048

typedef __attribute__((ext_vector_type(8))) short  short8v;
typedef __attribute__((ext_vector_type(4))) float  floatx4;

// float -> bf16 bits, round-to-nearest-even
__device__ __forceinline__ ushort f2bf(float x) {
  uint u = __builtin_bit_cast(uint, x);
  u = (u + 0x7FFFu + ((u >> 16) & 1u)) >> 16;
  return (ushort)u;
}
__device__ __forceinline__ float bf2f(ushort x) {
  return __builtin_bit_cast(float, (uint)x << 16);
}

__device__ __forceinline__ void gll16(const void* g, void* l) {
  __builtin_amdgcn_global_load_lds((const __attribute__((address_space(1))) void*)g,
                                   (__attribute__((address_space(3))) void*)l,
                                   16, 0, 0);
}

// ---------------- embedding + sinusoidal positional encoding (bf16 out) ----------------
__global__ __launch_bounds__(256) void embed_pe_kernel(const int* __restrict__ qids,
                                                       const float* __restrict__ emb,
                                                       ushort* __restrict__ x) {
  int idx = blockIdx.x * 256 + threadIdx.x;
  int d   = idx & (DD - 1);
  int row = idx >> 10;
  int s   = row % SQl;
  int tok = qids[row];
  float expo = (float)(d & ~1) * (1.0f / (float)DD);
  float dv   = powf(10000.0f, expo);
  float ang  = (float)s / dv;
  float pe   = (d & 1) ? cosf(ang) : sinf(ang);
  x[idx] = f2bf(emb[(size_t)tok * DD + d] + pe);
}

// ---------------- f32 -> bf16 elementwise ----------------
__global__ __launch_bounds__(256) void cvt_bf16_kernel(const float* __restrict__ in,
                                                       ushort* __restrict__ out, int n8) {
  int idx = blockIdx.x * 256 + threadIdx.x;
  if (idx >= n8) return;
  const floatx4 va = ((const floatx4*)in)[idx * 2];
  const floatx4 vb = ((const floatx4*)in)[idx * 2 + 1];
  short8v o;
  o[0] = (short)f2bf(va.x); o[1] = (short)f2bf(va.y);
  o[2] = (short)f2bf(va.z); o[3] = (short)f2bf(va.w);
  o[4] = (short)f2bf(vb.x); o[5] = (short)f2bf(vb.y);
  o[6] = (short)f2bf(vb.z); o[7] = (short)f2bf(vb.w);
  ((short8v*)out)[idx] = o;
}

// ---------------- batched transposes: W[K][N] f32 -> WT[N][K] bf16 ----------------
struct P8 { const float* p[8]; };
__global__ __launch_bounds__(256) void transpose48_kernel(P8 srcs, ushort* __restrict__ dst) {
  __shared__ float t[32][33];
  const size_t MEL = (size_t)DD * DD;
  const int z = blockIdx.z;
  const int arr = z / 6, l = z - arr * 6;
  const size_t base[8] = {0, MEL, 2*MEL, 18*MEL, 24*MEL, 30*MEL, 36*MEL, 42*MEL};
  const size_t lstr[8] = {3*MEL, 3*MEL, 3*MEL, MEL, MEL, MEL, MEL, MEL};
  const float* __restrict__ W = srcs.p[arr] + (size_t)l * MEL;
  ushort* __restrict__ WT = dst + base[arr] + (size_t)l * lstr[arr];
  const int n0 = blockIdx.x * 32, k0 = blockIdx.y * 32;
  const int tx = threadIdx.x & 31, ty = threadIdx.x >> 5;
#pragma unroll
  for (int i = 0; i < 4; ++i)
    t[ty + i * 8][tx] = W[(size_t)(k0 + ty + i * 8) * DD + n0 + tx];
  __syncthreads();
#pragma unroll
  for (int i = 0; i < 4; ++i)
    WT[(size_t)(n0 + ty + i * 8) * DD + k0 + tx] = f2bf(t[tx][ty + i * 8]);
}

__global__ __launch_bounds__(256) void transposeW_kernel(const float* __restrict__ src,
                                                         ushort* __restrict__ dst,
                                                         int K, int N) {
  __shared__ float t[32][33];
  const int z = blockIdx.z;
  const float* __restrict__ W = src + (size_t)z * K * N;
  ushort* __restrict__ WT = dst + (size_t)z * K * N;
  const int n0 = blockIdx.x * 32, k0 = blockIdx.y * 32;
  const int tx = threadIdx.x & 31, ty = threadIdx.x >> 5;
#pragma unroll
  for (int i = 0; i < 4; ++i)
    t[ty + i * 8][tx] = W[(size_t)(k0 + ty + i * 8) * N + n0 + tx];
  __syncthreads();
#pragma unroll
  for (int i = 0; i < 4; ++i)
    WT[(size_t)(n0 + ty + i * 8) * K + k0 + tx] = f2bf(t[tx][ty + i * 8]);
}

// ---------------- LayerNorm: wave per row (bf16 in; bf16 or f32 out) ----------------
template <int OBF16>
__global__ __launch_bounds__(256) void ln4_kernel(const ushort* __restrict__ in,
                                                  const float* __restrict__ gam,
                                                  const float* __restrict__ bet,
                                                  float* __restrict__ outf,
                                                  ushort* __restrict__ outb) {
  const int wid  = threadIdx.x >> 6;
  const int lane = threadIdx.x & 63;
  const int row  = blockIdx.x * 4 + wid;
  const ushort* ip = in + (size_t)row * DD;

  const short8v xa = ((const short8v*)ip)[lane];
  const short8v xb = ((const short8v*)ip)[64 + lane];
  float fa[8], fb[8];
  float s = 0.f, sq = 0.f;
#pragma unroll
  for (int e = 0; e < 8; ++e) {
    fa[e] = bf2f((ushort)xa[e]);
    fb[e] = bf2f((ushort)xb[e]);
    s  += fa[e] + fb[e];
    sq += fa[e] * fa[e] + fb[e] * fb[e];
  }
#pragma unroll
  for (int msk = 1; msk < 64; msk <<= 1) {
    s  += __shfl_xor(s,  msk, 64);
    sq += __shfl_xor(sq, msk, 64);
  }
  const float m   = s * (1.0f / (float)DD);
  const float var = sq * (1.0f / (float)DD) - m * m;
  const float inv = rsqrtf(var + 1e-9f);

  const int ca = lane * 8, cb_ = 512 + lane * 8;
  if (OBF16) {
    short8v oa, ob;
#pragma unroll
    for (int e = 0; e < 8; ++e) {
      oa[e] = (short)f2bf((fa[e] - m) * inv * gam[ca + e] + bet[ca + e]);
      ob[e] = (short)f2bf((fb[e] - m) * inv * gam[cb_ + e] + bet[cb_ + e]);
    }
    ((short8v*)&outb[(size_t)row * DD])[lane]      = oa;
    ((short8v*)&outb[(size_t)row * DD])[64 + lane] = ob;
  } else {
    float* op = outf + (size_t)row * DD;
#pragma unroll
    for (int e = 0; e < 8; ++e) {
      op[ca + e]  = (fa[e] - m) * inv * gam[ca + e] + bet[ca + e];
      op[cb_ + e] = (fb[e] - m) * inv * gam[cb_ + e] + bet[cb_ + e];
    }
  }
}

struct BiasP { const float* p[6]; };   // bias.p[col>>10][col&1023]

// ---------------- gemm128: r14 structure, NO XCD swizzle (A/B vs r15) ----------------
// 128x128 tile, 4 waves, BK=64, single 32KB buffer, 2 barriers/tile, static NT
// unroll, __launch_bounds__(256,4). r8 evidence: plain blockIdx mapping fetches
// 72 MB vs swizzle's 232 MB on the N=6144 shape; at 4 blocks/CU HBM is 43% of
// peak, so the over-fetch now costs time.
template <int RELU, int ACC, int NT>
__global__ __launch_bounds__(256, 4) void gemm128_mfma(const ushort* __restrict__ A,
                                                       const ushort* __restrict__ BT,
                                                       BiasP bias,
                                                       ushort* __restrict__ Cb,
                                                       int ldc) {
  constexpr int K = NT * 64;
  __shared__ short8v As[1024];   // 16 KB : [128 rows][8 slots]
  __shared__ short8v Bs[1024];   // 16 KB
  const int tid  = threadIdx.x;
  const int wid  = tid >> 6;
  const int lane = tid & 63;
  const int bn = blockIdx.x * 128;
  const int bm = blockIdx.y * 128;

  const int wm = (wid >> 1) * 64;
  const int wn = (wid & 1) * 64;
  const int lq = lane & 15;
  const int lg = lane >> 4;

  const ushort* aS[4];
  const ushort* bS[4];
#pragma unroll
  for (int i = 0; i < 4; ++i) {
    const int s   = i * 256 + wid * 64 + lane;
    const int row = s >> 3;
    const int kg  = (s & 7) ^ (row & 7);
    aS[i] = A  + (size_t)(bm + row) * K + kg * 8;
    bS[i] = BT + (size_t)(bn + row) * K + kg * 8;
  }

  int aIdx[4], bIdx[4];
#pragma unroll
  for (int i = 0; i < 4; ++i) {
    const int mr = wm + i * 16 + lq;
    aIdx[i] = mr * 8 + (lg ^ (mr & 7));
    const int nr = wn + i * 16 + lq;
    bIdx[i] = nr * 8 + (lg ^ (nr & 7));
  }

  floatx4 acc[4][4];
  const floatx4 fz = {0.f, 0.f, 0.f, 0.f};
#pragma unroll
  for (int mi = 0; mi < 4; ++mi)
#pragma unroll
    for (int ni = 0; ni < 4; ++ni) acc[mi][ni] = fz;

#pragma unroll
  for (int t = 0; t < NT; ++t) {
    const int ko = t * 64;
#pragma unroll
    for (int i = 0; i < 4; ++i) gll16(aS[i] + ko, &As[i * 256 + wid * 64]);
#pragma unroll
    for (int i = 0; i < 4; ++i) gll16(bS[i] + ko, &Bs[i * 256 + wid * 64]);
    __syncthreads();                       // drains vmcnt; LDS ready
#pragma unroll
    for (int kk = 0; kk < 2; ++kk) {
      short8v af[4], bf_[4];
#pragma unroll
      for (int i = 0; i < 4; ++i) {
        af[i]  = As[aIdx[i] ^ (kk * 4)];
        bf_[i] = Bs[bIdx[i] ^ (kk * 4)];
      }
#pragma unroll
      for (int mi = 0; mi < 4; ++mi)
#pragma unroll
        for (int ni = 0; ni < 4; ++ni)
          acc[mi][ni] = __builtin_amdgcn_mfma_f32_16x16x32_bf16(af[mi], bf_[ni], acc[mi][ni], 0, 0, 0);
    }
    __syncthreads();                       // reads done before next overwrite
  }

  // epilogue: C/D frag col = lane&15, row = (lane>>4)*4 + reg
#pragma unroll
  for (int mi = 0; mi < 4; ++mi) {
    const int row = bm + wm + mi * 16 + lg * 4;
#pragma unroll
    for (int ni = 0; ni < 4; ++ni) {
      const int col = bn + wn + ni * 16 + lq;
      const float* bp = bias.p[col >> 10];
      const float bvv = bp ? bp[col & (DD - 1)] : 0.f;
#pragma unroll
      for (int r = 0; r < 4; ++r) {
        float val = acc[mi][ni][r] + bvv;
        if (ACC)  val += bf2f(Cb[(size_t)(row + r) * ldc + col]);
        if (RELU) val = fmaxf(val, 0.f);
        Cb[(size_t)(row + r) * ldc + col] = f2bf(val);
      }
    }
  }
}

// modes: 1 = bf16 ACC (+bias), 2 = bf16 + relu, 3 = bf16
static inline void launch_g(const ushort* A, const ushort* BT, BiasP bias,
                            ushort* Cb, int M, int N, int K, int ldc,
                            int mode, hipStream_t s) {
  dim3 grid(N / 128, M / 128), blk(256);
  if (K == 2048) {       // FF2 (always mode 1)
    gemm128_mfma<0, 1, 32><<<grid, blk, 0, s>>>(A, BT, bias, Cb, ldc);
  } else if (mode == 1) {
    gemm128_mfma<0, 1, 16><<<grid, blk, 0, s>>>(A, BT, bias, Cb, ldc);
  } else if (mode == 2) {
    gemm128_mfma<1, 0, 16><<<grid, blk, 0, s>>>(A, BT, bias, Cb, ldc);
  } else {
    gemm128_mfma<0, 0, 16><<<grid, blk, 0, s>>>(A, BT, bias, Cb, ldc);
  }
}

// ---------------- MFMA flash attention: swapped-QK^T (S^T), vectorized P writes ----
template <int CAUSAL>
__global__ __launch_bounds__(256, 2) void attn_mfma_kernel(const ushort* __restrict__ q, int qs,
                                                           const ushort* __restrict__ k, int ks,
                                                           const ushort* __restrict__ v, int vs,
                                                           const int* __restrict__ qids,
                                                           ushort* __restrict__ out) {
  __shared__ short8v Kl[208 * 8];     // 26.6 KB
  __shared__ ushort  Vt[64 * 256];    // 32 KB
  __shared__ ushort  Pw[16 * 640];    // 20 KB : [tile][qrow 0..15][40]
  __shared__ float   padf[224];

  const int bh   = blockIdx.x;
  const int h    = bh & (NH - 1);
  const int b    = bh >> 4;
  const int tid  = threadIdx.x;
  const int w    = tid >> 6;
  const int lane = tid & 63;
  const int lq   = lane & 15;
  const int lg   = lane >> 4;

  if (tid < 208) {
    const int kp = tid;
    if (kp < SKV) {
      const short8v* src = (const short8v*)(k + ((size_t)(b * SKV + kp)) * ks + h * HDm);
#pragma unroll
      for (int s = 0; s < 8; ++s) Kl[kp * 8 + (s ^ (kp & 7))] = src[s];
    } else {
      const short8v z = {0, 0, 0, 0, 0, 0, 0, 0};
#pragma unroll
      for (int s = 0; s < 8; ++s) Kl[kp * 8 + s] = z;
    }
  }
  if (tid < 224) {
    const int kp = tid;
    float pf = 1.f;
    if (kp < SKV) {
      pf = CAUSAL ? ((qids[b * SQl + kp] == 0) ? 1.f : 0.f) : 0.f;
      const short8v* src = (const short8v*)(v + ((size_t)(b * SKV + kp)) * vs + h * HDm);
      const int s3 = kp >> 3, k7 = kp & 7;
#pragma unroll
      for (int li = 0; li < 8; ++li) {
        const short8v vv = src[li];
#pragma unroll
        for (int e = 0; e < 8; ++e)
          Vt[(li * 8 + e) * 256 + ((s3 ^ e) * 8) + k7] = (ushort)vv[e];
      }
    } else {
      const int s3 = kp >> 3, k7 = kp & 7;
#pragma unroll
      for (int li = 0; li < 8; ++li)
#pragma unroll
        for (int e = 0; e < 8; ++e)
          Vt[(li * 8 + e) * 256 + ((s3 ^ e) * 8) + k7] = 0;
    }
    padf[kp] = pf;
  }
  __syncthreads();

  short8v qf[4][2];
#pragma unroll
  for (int i = 0; i < 4; ++i) {
    const int mt = i * 4 + w;
    if (mt > 12) continue;
    int qrow = mt * 16 + lq;
    if (qrow > SQl - 1) qrow = SQl - 1;
    const ushort* qp = q + ((size_t)(b * SQl + qrow)) * qs + h * HDm + lg * 8;
    qf[i][0] = *(const short8v*)qp;
    qf[i][1] = *(const short8v*)(qp + 32);
  }

  float m_[4], rsP[4];
  floatx4 Of[4][4];
  const floatx4 fz = {0.f, 0.f, 0.f, 0.f};
#pragma unroll
  for (int i = 0; i < 4; ++i) {
    m_[i] = -3e38f; rsP[i] = 0.f;
#pragma unroll
    for (int dt = 0; dt < 4; ++dt) Of[i][dt] = fz;
  }

  for (int kc = 0; kc < 7; ++kc) {
    floatx4 sv[2][4];
#pragma unroll
    for (int t = 0; t < 2; ++t) {
      const int kt = kc * 2 + t;
      const bool valid = (kt < 13);
      short8v bk0, bk1;
      if (valid) {
        const int kpl = kt * 16 + lq;
        bk0 = Kl[kpl * 8 + (lg ^ (kpl & 7))];
        bk1 = Kl[kpl * 8 + ((4 + lg) ^ (kpl & 7))];
      }
      float pm[4];
#pragma unroll
      for (int r = 0; r < 4; ++r)
        pm[r] = valid ? padf[kt * 16 + lg * 4 + r] : 1.f;
#pragma unroll
      for (int i = 0; i < 4; ++i) {
        const int mt = i * 4 + w;
        floatx4 S = {0.f, 0.f, 0.f, 0.f};
        if (valid && mt <= 12) {
          S = __builtin_amdgcn_mfma_f32_16x16x32_bf16(bk0, qf[i][0], S, 0, 0, 0);
          S = __builtin_amdgcn_mfma_f32_16x16x32_bf16(bk1, qf[i][1], S, 0, 0, 0);
        }
        const int qrow = mt * 16 + lq;
#pragma unroll
        for (int r = 0; r < 4; ++r) {
          const int kp = kt * 16 + lg * 4 + r;
          bool masked = (!valid) || (mt > 12) || (pm[r] != 0.f);
          if (CAUSAL) masked = masked || (kp > qrow);
          sv[t][i][r] = masked ? -3e38f : S[r] * 0.125f;
        }
      }
    }

    bool trig = false;
#pragma unroll
    for (int t = 0; t < 2; ++t)
#pragma unroll
      for (int i = 0; i < 4; ++i)
#pragma unroll
        for (int r = 0; r < 4; ++r)
          trig = trig || (sv[t][i][r] > m_[i] + 8.f);
    if (__any(trig)) {
#pragma unroll
      for (int i = 0; i < 4; ++i) {
        float tm = -3e38f;
#pragma unroll
        for (int t = 0; t < 2; ++t)
#pragma unroll
          for (int r = 0; r < 4; ++r) tm = fmaxf(tm, sv[t][i][r]);
        tm = fmaxf(tm, __shfl_xor(tm, 16, 64));
        tm = fmaxf(tm, __shfl_xor(tm, 32, 64));
        const float mn = fmaxf(m_[i], tm);
        const float sc = __expf(m_[i] - mn);
        rsP[i] *= sc;
#pragma unroll
        for (int r = 0; r < 4; ++r) {
          const float scq = __shfl(sc, lg * 4 + r, 64);
#pragma unroll
          for (int dt = 0; dt < 4; ++dt) Of[i][dt][r] *= scq;
        }
        m_[i] = mn;
      }
    }

#pragma unroll
    for (int t = 0; t < 2; ++t)
#pragma unroll
      for (int i = 0; i < 4; ++i) {
        const int mt = i * 4 + w;
        if (mt > 12) continue;
        float p[4];
#pragma unroll
        for (int r = 0; r < 4; ++r) {
          const float s = sv[t][i][r];
          p[r] = (s < -1e37f) ? 0.f : __expf(s - m_[i]);
          rsP[i] += p[r];
        }
        uint2 pk;
        pk.x = (uint)f2bf(p[0]) | ((uint)f2bf(p[1]) << 16);
        pk.y = (uint)f2bf(p[2]) | ((uint)f2bf(p[3]) << 16);
        *(uint2*)&Pw[(w * 4 + i) * 640 + lq * 40 + t * 16 + lg * 4] = pk;
      }

    short8v vb[4];
#pragma unroll
    for (int dt = 0; dt < 4; ++dt) {
      const int d  = dt * 16 + lq;
      const int sk = kc * 4 + lg;
      vb[dt] = ((const short8v*)Vt)[d * 32 + (sk ^ (d & 7))];
    }
#pragma unroll
    for (int i = 0; i < 4; ++i) {
      const int mt = i * 4 + w;
      if (mt > 12) continue;
      const short8v pa = *(const short8v*)&Pw[(w * 4 + i) * 640 + lq * 40 + lg * 8];
#pragma unroll
      for (int dt = 0; dt < 4; ++dt)
        Of[i][dt] = __builtin_amdgcn_mfma_f32_16x16x32_bf16(pa, vb[dt], Of[i][dt], 0, 0, 0);
    }
  }

#pragma unroll
  for (int i = 0; i < 4; ++i) {
    const int mt = i * 4 + w;
    if (mt > 12) continue;
    float rowsum = rsP[i];
    rowsum += __shfl_xor(rowsum, 16, 64);
    rowsum += __shfl_xor(rowsum, 32, 64);
#pragma unroll
    for (int r = 0; r < 4; ++r) {
      const float rs = __shfl(rowsum, lg * 4 + r, 64);
      const int qrow = mt * 16 + lg * 4 + r;
      if (qrow >= SQl) continue;
      const float linv = 1.0f / rs;
      ushort* op = out + ((size_t)(b * SQl + qrow)) * DD + h * HDm;
#pragma unroll
      for (int dt = 0; dt < 4; ++dt)
        op[dt * 16 + lq] = f2bf(Of[i][dt][r] * linv);
    }
  }
}

// ---------------- driver ----------------
extern "C" void kernel_launch(void* const* d_in, const int* in_sizes, int n_in,
                              void* d_out, int out_size, void* d_ws, size_t ws_size,
                              hipStream_t stream) {
  (void)in_sizes; (void)n_in; (void)out_size; (void)ws_size;

  const int*   qids  = (const int*)  d_in[0];
  const float* key   = (const float*)d_in[1];
  const float* value = (const float*)d_in[2];
  const float* emb   = (const float*)d_in[3];
  const float* ln1_g = (const float*)d_in[4];
  const float* ln2_g = (const float*)d_in[5];
  const float* ln3_g = (const float*)d_in[6];
  const float* ln1_b = (const float*)d_in[7];
  const float* ln2_b = (const float*)d_in[8];
  const float* ln3_b = (const float*)d_in[9];
  const float* Wq_s  = (const float*)d_in[10];
  const float* Wk_s  = (const float*)d_in[11];
  const float* Wv_s  = (const float*)d_in[12];
  const float* Wo_s  = (const float*)d_in[13];
  const float* Wq_c  = (const float*)d_in[14];
  const float* Wk_c  = (const float*)d_in[15];
  const float* Wv_c  = (const float*)d_in[16];
  const float* Wo_c  = (const float*)d_in[17];
  const float* bq_s  = (const float*)d_in[18];
  const float* bk_s  = (const float*)d_in[19];
  const float* bv_s  = (const float*)d_in[20];
  const float* bq_c  = (const float*)d_in[21];
  const float* bk_c  = (const float*)d_in[22];
  const float* bv_c  = (const float*)d_in[23];
  const float* W1    = (const float*)d_in[24];
  const float* bf1   = (const float*)d_in[25];
  const float* W2    = (const float*)d_in[26];
  const float* bf2   = (const float*)d_in[27];
  const float* lnf_g = (const float*)d_in[28];
  const float* lnf_b = (const float*)d_in[29];

  const size_t NTOK = (size_t)BB * SQl * DD;     // 6,553,600
  const size_t MEL  = (size_t)DD * DD;
  char* w = (char*)d_ws;
  ushort* o    = (ushort*)w; w += NTOK * 2;      // bf16 residual stream
  ushort* t0b  = (ushort*)w; w += NTOK * 2;
  ushort* qkv  = (ushort*)w; w += (size_t)BB * SQl * 3 * DD * 2;
  ushort* kc   = (ushort*)w; w += (size_t)BB * SQl * 6 * DD * 2;
  ushort* vc   = (ushort*)w; w += (size_t)BB * SQl * 6 * DD * 2;
  ushort* kb   = (ushort*)w; w += NTOK * 2;
  ushort* vb   = (ushort*)w; w += NTOK * 2;
  ushort* fbb  = (ushort*)w; w += (size_t)BB * SQl * FFD * 2;
  ushort* wt   = (ushort*)w; w += 48 * MEL * 2;
  ushort* wt1  = (ushort*)w; w += (size_t)NL * DD * FFD * 2;
  ushort* wt2  = (ushort*)w; w += (size_t)NL * FFD * DD * 2;

  const int M = BB * SQl;                        // 6400
  const BiasP nob = {{nullptr, nullptr, nullptr, nullptr, nullptr, nullptr}};

  embed_pe_kernel<<<(int)(NTOK / 256), 256, 0, stream>>>(qids, emb, o);
  cvt_bf16_kernel<<<(int)(NTOK / 8 + 255) / 256, 256, 0, stream>>>(key,   kb, (int)(NTOK / 8));
  cvt_bf16_kernel<<<(int)(NTOK / 8 + 255) / 256, 256, 0, stream>>>(value, vb, (int)(NTOK / 8));

  P8 p8 = {{Wq_s, Wk_s, Wv_s, Wo_s, Wq_c, Wk_c, Wv_c, Wo_c}};
  transpose48_kernel<<<dim3(32, 32, 48), 256, 0, stream>>>(p8, wt);
  transposeW_kernel<<<dim3(FFD / 32, DD / 32, NL), 256, 0, stream>>>(W1, wt1, DD, FFD);
  transposeW_kernel<<<dim3(DD / 32, FFD / 32, NL), 256, 0, stream>>>(W2, wt2, FFD, DD);

  ushort* wtQKV = wt;                 // [l][3M]
  ushort* wtOs  = wt + 18 * MEL;      // [l][1M]
  ushort* wtQc  = wt + 24 * MEL;
  ushort* wtKc  = wt + 30 * MEL;
  ushort* wtVc  = wt + 36 * MEL;
  ushort* wtOc  = wt + 42 * MEL;

  // cross-attention K/V for ALL layers (layer-invariant A): two N=6144 GEMMs
  {
    BiasP bk6, bv6;
#pragma unroll
    for (int l = 0; l < NL; ++l) { bk6.p[l] = bk_c + l * DD; bv6.p[l] = bv_c + l * DD; }
    launch_g(kb, wtKc, bk6, kc, M, 6 * DD, DD, 6 * DD, 3, stream);
    launch_g(vb, wtVc, bv6, vc, M, 6 * DD, DD, 6 * DD, 3, stream);
  }

  for (int l = 0; l < NL; ++l) {
    // ---- self-attention ----
    ln4_kernel<1><<<M / 4, 256, 0, stream>>>(o, ln1_g + l * DD, ln1_b + l * DD, nullptr, t0b);
    BiasP bqkv = {{bq_s + l * DD, bk_s + l * DD, bv_s + l * DD, nullptr, nullptr, nullptr}};
    launch_g(t0b, wtQKV + l * 3 * MEL, bqkv, qkv, M, 3 * DD, DD, 3 * DD, 3, stream);
    attn_mfma_kernel<1><<<BB * NH, 256, 0, stream>>>(qkv, 3 * DD, qkv + DD, 3 * DD,
                                                     qkv + 2 * DD, 3 * DD, qids, t0b);
    launch_g(t0b, wtOs + l * MEL, nob, o, M, DD, DD, DD, 1, stream);

    // ---- cross-attention ----
    ln4_kernel<1><<<M / 4, 256, 0, stream>>>(o, ln2_g + l * DD, ln2_b + l * DD, nullptr, t0b);
    BiasP bqc = {{bq_c + l * DD, nullptr, nullptr, nullptr, nullptr, nullptr}};
    launch_g(t0b, wtQc + l * MEL, bqc, qkv, M, DD, DD, 3 * DD, 3, stream);
    attn_mfma_kernel<0><<<BB * NH, 256, 0, stream>>>(qkv, 3 * DD, kc + l * DD, 6 * DD,
                                                     vc + l * DD, 6 * DD, nullptr, t0b);
    launch_g(t0b, wtOc + l * MEL, nob, o, M, DD, DD, DD, 1, stream);

    // ---- feed-forward ----
    ln4_kernel<1><<<M / 4, 256, 0, stream>>>(o, ln3_g + l * DD, ln3_b + l * DD, nullptr, t0b);
    BiasP bf1p = {{bf1 + l * FFD, bf1 + l * FFD + DD, nullptr, nullptr, nullptr, nullptr}};
    launch_g(t0b, wt1 + (size_t)l * DD * FFD, bf1p, fbb, M, FFD, DD, FFD, 2, stream);
    BiasP bf2p = {{bf2 + l * DD, nullptr, nullptr, nullptr, nullptr, nullptr}};
    launch_g(fbb, wt2 + (size_t)l * FFD * DD, bf2p, o, M, DD, FFD, DD, 1, stream);
  }

  ln4_kernel<0><<<M / 4, 256, 0, stream>>>(o, lnf_g, lnf_b, (float*)d_out, nullptr);
}

// Round 17
// 2211.207 us; speedup vs baseline: 1.0545x; 1.0545x over previous
//
#include <hip/hip_runtime.h>
#include <math.h>

#define BB  32
#define SQl 200
#define SKV 200
#define DD  1024
#define NH  16
#define HDm 64
#define NL  6
#define FFD 2048

typedef __attribute__((ext_vector_type(8))) short  short8v;
typedef __attribute__((ext_vector_type(4))) float  floatx4;

// float -> bf16 bits, round-to-nearest-even
__device__ __forceinline__ ushort f2bf(float x) {
  uint u = __builtin_bit_cast(uint, x);
  u = (u + 0x7FFFu + ((u >> 16) & 1u)) >> 16;
  return (ushort)u;
}
__device__ __forceinline__ float bf2f(ushort x) {
  return __builtin_bit_cast(float, (uint)x << 16);
}

__device__ __forceinline__ void gll16(const void* g, void* l) {
  __builtin_amdgcn_global_load_lds((const __attribute__((address_space(1))) void*)g,
                                   (__attribute__((address_space(3))) void*)l,
                                   16, 0, 0);
}

// ---------------- embedding + sinusoidal positional encoding (bf16 out) ----------------
__global__ __launch_bounds__(256) void embed_pe_kernel(const int* __restrict__ qids,
                                                       const float* __restrict__ emb,
                                                       ushort* __restrict__ x) {
  int idx = blockIdx.x * 256 + threadIdx.x;
  int d   = idx & (DD - 1);
  int row = idx >> 10;
  int s   = row % SQl;
  int tok = qids[row];
  float expo = (float)(d & ~1) * (1.0f / (float)DD);
  float dv   = powf(10000.0f, expo);
  float ang  = (float)s / dv;
  float pe   = (d & 1) ? cosf(ang) : sinf(ang);
  x[idx] = f2bf(emb[(size_t)tok * DD + d] + pe);
}

// ---------------- f32 -> bf16 elementwise ----------------
__global__ __launch_bounds__(256) void cvt_bf16_kernel(const float* __restrict__ in,
                                                       ushort* __restrict__ out, int n8) {
  int idx = blockIdx.x * 256 + threadIdx.x;
  if (idx >= n8) return;
  const floatx4 va = ((const floatx4*)in)[idx * 2];
  const floatx4 vb = ((const floatx4*)in)[idx * 2 + 1];
  short8v o;
  o[0] = (short)f2bf(va.x); o[1] = (short)f2bf(va.y);
  o[2] = (short)f2bf(va.z); o[3] = (short)f2bf(va.w);
  o[4] = (short)f2bf(vb.x); o[5] = (short)f2bf(vb.y);
  o[6] = (short)f2bf(vb.z); o[7] = (short)f2bf(vb.w);
  ((short8v*)out)[idx] = o;
}

// ---------------- batched transposes: W[K][N] f32 -> WT[N][K] bf16 ----------------
struct P8 { const float* p[8]; };
__global__ __launch_bounds__(256) void transpose48_kernel(P8 srcs, ushort* __restrict__ dst) {
  __shared__ float t[32][33];
  const size_t MEL = (size_t)DD * DD;
  const int z = blockIdx.z;
  const int arr = z / 6, l = z - arr * 6;
  const size_t base[8] = {0, MEL, 2*MEL, 18*MEL, 24*MEL, 30*MEL, 36*MEL, 42*MEL};
  const size_t lstr[8] = {3*MEL, 3*MEL, 3*MEL, MEL, MEL, MEL, MEL, MEL};
  const float* __restrict__ W = srcs.p[arr] + (size_t)l * MEL;
  ushort* __restrict__ WT = dst + base[arr] + (size_t)l * lstr[arr];
  const int n0 = blockIdx.x * 32, k0 = blockIdx.y * 32;
  const int tx = threadIdx.x & 31, ty = threadIdx.x >> 5;
#pragma unroll
  for (int i = 0; i < 4; ++i)
    t[ty + i * 8][tx] = W[(size_t)(k0 + ty + i * 8) * DD + n0 + tx];
  __syncthreads();
#pragma unroll
  for (int i = 0; i < 4; ++i)
    WT[(size_t)(n0 + ty + i * 8) * DD + k0 + tx] = f2bf(t[tx][ty + i * 8]);
}

__global__ __launch_bounds__(256) void transposeW_kernel(const float* __restrict__ src,
                                                         ushort* __restrict__ dst,
                                                         int K, int N) {
  __shared__ float t[32][33];
  const int z = blockIdx.z;
  const float* __restrict__ W = src + (size_t)z * K * N;
  ushort* __restrict__ WT = dst + (size_t)z * K * N;
  const int n0 = blockIdx.x * 32, k0 = blockIdx.y * 32;
  const int tx = threadIdx.x & 31, ty = threadIdx.x >> 5;
#pragma unroll
  for (int i = 0; i < 4; ++i)
    t[ty + i * 8][tx] = W[(size_t)(k0 + ty + i * 8) * N + n0 + tx];
  __syncthreads();
#pragma unroll
  for (int i = 0; i < 4; ++i)
    WT[(size_t)(n0 + ty + i * 8) * K + k0 + tx] = f2bf(t[tx][ty + i * 8]);
}

// ---------------- LayerNorm: wave per row (bf16 in; bf16 or f32 out) ----------------
template <int OBF16>
__global__ __launch_bounds__(256) void ln4_kernel(const ushort* __restrict__ in,
                                                  const float* __restrict__ gam,
                                                  const float* __restrict__ bet,
                                                  float* __restrict__ outf,
                                                  ushort* __restrict__ outb) {
  const int wid  = threadIdx.x >> 6;
  const int lane = threadIdx.x & 63;
  const int row  = blockIdx.x * 4 + wid;
  const ushort* ip = in + (size_t)row * DD;

  const short8v xa = ((const short8v*)ip)[lane];
  const short8v xb = ((const short8v*)ip)[64 + lane];
  float fa[8], fb[8];
  float s = 0.f, sq = 0.f;
#pragma unroll
  for (int e = 0; e < 8; ++e) {
    fa[e] = bf2f((ushort)xa[e]);
    fb[e] = bf2f((ushort)xb[e]);
    s  += fa[e] + fb[e];
    sq += fa[e] * fa[e] + fb[e] * fb[e];
  }
#pragma unroll
  for (int msk = 1; msk < 64; msk <<= 1) {
    s  += __shfl_xor(s,  msk, 64);
    sq += __shfl_xor(sq, msk, 64);
  }
  const float m   = s * (1.0f / (float)DD);
  const float var = sq * (1.0f / (float)DD) - m * m;
  const float inv = rsqrtf(var + 1e-9f);

  const int ca = lane * 8, cb_ = 512 + lane * 8;
  if (OBF16) {
    short8v oa, ob;
#pragma unroll
    for (int e = 0; e < 8; ++e) {
      oa[e] = (short)f2bf((fa[e] - m) * inv * gam[ca + e] + bet[ca + e]);
      ob[e] = (short)f2bf((fb[e] - m) * inv * gam[cb_ + e] + bet[cb_ + e]);
    }
    ((short8v*)&outb[(size_t)row * DD])[lane]      = oa;
    ((short8v*)&outb[(size_t)row * DD])[64 + lane] = ob;
  } else {
    float* op = outf + (size_t)row * DD;
#pragma unroll
    for (int e = 0; e < 8; ++e) {
      op[ca + e]  = (fa[e] - m) * inv * gam[ca + e] + bet[ca + e];
      op[cb_ + e] = (fb[e] - m) * inv * gam[cb_ + e] + bet[cb_ + e];
    }
  }
}

struct BiasP { const float* p[6]; };   // bias.p[col>>10][col&1023]

// ---------------- gemm128: r14 structure, shape-dependent XCD swizzle ----------------
// 128x128 tile, 4 waves, BK=64, single 32KB buffer, 2 barriers/tile, static NT
// unroll, __launch_bounds__(256,4). SWZ=1 (chunked XCD swizzle) for small-N
// shapes (r15/r16 A/B: helps L2 locality when B-panel is narrow); SWZ=0 for
// N=6144 (swizzle caused 3x over-fetch there: 270 vs 70 MB, ~7us/dispatch).
template <int RELU, int ACC, int NT, int SWZ>
__global__ __launch_bounds__(256, 4) void gemm128_mfma(const ushort* __restrict__ A,
                                                       const ushort* __restrict__ BT,
                                                       BiasP bias,
                                                       ushort* __restrict__ Cb,
                                                       int ldc) {
  constexpr int K = NT * 64;
  __shared__ short8v As[1024];   // 16 KB : [128 rows][8 slots]
  __shared__ short8v Bs[1024];   // 16 KB
  const int tid  = threadIdx.x;
  const int wid  = tid >> 6;
  const int lane = tid & 63;

  int bn, bm;
  if (SWZ) {
    const int nwg = gridDim.x * gridDim.y;
    int wg = blockIdx.y * gridDim.x + blockIdx.x;
    wg = (wg & 7) * (nwg >> 3) + (wg >> 3);
    bn = (wg % gridDim.x) * 128;
    bm = (wg / gridDim.x) * 128;
  } else {
    bn = blockIdx.x * 128;
    bm = blockIdx.y * 128;
  }

  const int wm = (wid >> 1) * 64;
  const int wn = (wid & 1) * 64;
  const int lq = lane & 15;
  const int lg = lane >> 4;

  const ushort* aS[4];
  const ushort* bS[4];
#pragma unroll
  for (int i = 0; i < 4; ++i) {
    const int s   = i * 256 + wid * 64 + lane;
    const int row = s >> 3;
    const int kg  = (s & 7) ^ (row & 7);
    aS[i] = A  + (size_t)(bm + row) * K + kg * 8;
    bS[i] = BT + (size_t)(bn + row) * K + kg * 8;
  }

  int aIdx[4], bIdx[4];
#pragma unroll
  for (int i = 0; i < 4; ++i) {
    const int mr = wm + i * 16 + lq;
    aIdx[i] = mr * 8 + (lg ^ (mr & 7));
    const int nr = wn + i * 16 + lq;
    bIdx[i] = nr * 8 + (lg ^ (nr & 7));
  }

  floatx4 acc[4][4];
  const floatx4 fz = {0.f, 0.f, 0.f, 0.f};
#pragma unroll
  for (int mi = 0; mi < 4; ++mi)
#pragma unroll
    for (int ni = 0; ni < 4; ++ni) acc[mi][ni] = fz;

#pragma unroll
  for (int t = 0; t < NT; ++t) {
    const int ko = t * 64;
#pragma unroll
    for (int i = 0; i < 4; ++i) gll16(aS[i] + ko, &As[i * 256 + wid * 64]);
#pragma unroll
    for (int i = 0; i < 4; ++i) gll16(bS[i] + ko, &Bs[i * 256 + wid * 64]);
    __syncthreads();                       // drains vmcnt; LDS ready
#pragma unroll
    for (int kk = 0; kk < 2; ++kk) {
      short8v af[4], bf_[4];
#pragma unroll
      for (int i = 0; i < 4; ++i) {
        af[i]  = As[aIdx[i] ^ (kk * 4)];
        bf_[i] = Bs[bIdx[i] ^ (kk * 4)];
      }
#pragma unroll
      for (int mi = 0; mi < 4; ++mi)
#pragma unroll
        for (int ni = 0; ni < 4; ++ni)
          acc[mi][ni] = __builtin_amdgcn_mfma_f32_16x16x32_bf16(af[mi], bf_[ni], acc[mi][ni], 0, 0, 0);
    }
    __syncthreads();                       // reads done before next overwrite
  }

  // epilogue: C/D frag col = lane&15, row = (lane>>4)*4 + reg
#pragma unroll
  for (int mi = 0; mi < 4; ++mi) {
    const int row = bm + wm + mi * 16 + lg * 4;
#pragma unroll
    for (int ni = 0; ni < 4; ++ni) {
      const int col = bn + wn + ni * 16 + lq;
      const float* bp = bias.p[col >> 10];
      const float bvv = bp ? bp[col & (DD - 1)] : 0.f;
#pragma unroll
      for (int r = 0; r < 4; ++r) {
        float val = acc[mi][ni][r] + bvv;
        if (ACC)  val += bf2f(Cb[(size_t)(row + r) * ldc + col]);
        if (RELU) val = fmaxf(val, 0.f);
        Cb[(size_t)(row + r) * ldc + col] = f2bf(val);
      }
    }
  }
}

// modes: 1 = bf16 ACC (+bias), 2 = bf16 + relu, 3 = bf16
static inline void launch_g(const ushort* A, const ushort* BT, BiasP bias,
                            ushort* Cb, int M, int N, int K, int ldc,
                            int mode, hipStream_t s) {
  dim3 grid(N / 128, M / 128), blk(256);
  if (N == 6144) {       // big cross-KV GEMMs: no swizzle (r16 A/B)
    gemm128_mfma<0, 0, 16, 0><<<grid, blk, 0, s>>>(A, BT, bias, Cb, ldc);
  } else if (K == 2048) {       // FF2 (always mode 1)
    gemm128_mfma<0, 1, 32, 1><<<grid, blk, 0, s>>>(A, BT, bias, Cb, ldc);
  } else if (mode == 1) {
    gemm128_mfma<0, 1, 16, 1><<<grid, blk, 0, s>>>(A, BT, bias, Cb, ldc);
  } else if (mode == 2) {
    gemm128_mfma<1, 0, 16, 1><<<grid, blk, 0, s>>>(A, BT, bias, Cb, ldc);
  } else {
    gemm128_mfma<0, 0, 16, 1><<<grid, blk, 0, s>>>(A, BT, bias, Cb, ldc);
  }
}

// ---------------- MFMA flash attention: swapped-QK^T (S^T), vectorized P writes ----
template <int CAUSAL>
__global__ __launch_bounds__(256, 2) void attn_mfma_kernel(const ushort* __restrict__ q, int qs,
                                                           const ushort* __restrict__ k, int ks,
                                                           const ushort* __restrict__ v, int vs,
                                                           const int* __restrict__ qids,
                                                           ushort* __restrict__ out) {
  __shared__ short8v Kl[208 * 8];     // 26.6 KB
  __shared__ ushort  Vt[64 * 256];    // 32 KB
  __shared__ ushort  Pw[16 * 640];    // 20 KB : [tile][qrow 0..15][40]
  __shared__ float   padf[224];

  const int bh   = blockIdx.x;
  const int h    = bh & (NH - 1);
  const int b    = bh >> 4;
  const int tid  = threadIdx.x;
  const int w    = tid >> 6;
  const int lane = tid & 63;
  const int lq   = lane & 15;
  const int lg   = lane >> 4;

  if (tid < 208) {
    const int kp = tid;
    if (kp < SKV) {
      const short8v* src = (const short8v*)(k + ((size_t)(b * SKV + kp)) * ks + h * HDm);
#pragma unroll
      for (int s = 0; s < 8; ++s) Kl[kp * 8 + (s ^ (kp & 7))] = src[s];
    } else {
      const short8v z = {0, 0, 0, 0, 0, 0, 0, 0};
#pragma unroll
      for (int s = 0; s < 8; ++s) Kl[kp * 8 + s] = z;
    }
  }
  if (tid < 224) {
    const int kp = tid;
    float pf = 1.f;
    if (kp < SKV) {
      pf = CAUSAL ? ((qids[b * SQl + kp] == 0) ? 1.f : 0.f) : 0.f;
      const short8v* src = (const short8v*)(v + ((size_t)(b * SKV + kp)) * vs + h * HDm);
      const int s3 = kp >> 3, k7 = kp & 7;
#pragma unroll
      for (int li = 0; li < 8; ++li) {
        const short8v vv = src[li];
#pragma unroll
        for (int e = 0; e < 8; ++e)
          Vt[(li * 8 + e) * 256 + ((s3 ^ e) * 8) + k7] = (ushort)vv[e];
      }
    } else {
      const int s3 = kp >> 3, k7 = kp & 7;
#pragma unroll
      for (int li = 0; li < 8; ++li)
#pragma unroll
        for (int e = 0; e < 8; ++e)
          Vt[(li * 8 + e) * 256 + ((s3 ^ e) * 8) + k7] = 0;
    }
    padf[kp] = pf;
  }
  __syncthreads();

  short8v qf[4][2];
#pragma unroll
  for (int i = 0; i < 4; ++i) {
    const int mt = i * 4 + w;
    if (mt > 12) continue;
    int qrow = mt * 16 + lq;
    if (qrow > SQl - 1) qrow = SQl - 1;
    const ushort* qp = q + ((size_t)(b * SQl + qrow)) * qs + h * HDm + lg * 8;
    qf[i][0] = *(const short8v*)qp;
    qf[i][1] = *(const short8v*)(qp + 32);
  }

  float m_[4], rsP[4];
  floatx4 Of[4][4];
  const floatx4 fz = {0.f, 0.f, 0.f, 0.f};
#pragma unroll
  for (int i = 0; i < 4; ++i) {
    m_[i] = -3e38f; rsP[i] = 0.f;
#pragma unroll
    for (int dt = 0; dt < 4; ++dt) Of[i][dt] = fz;
  }

  for (int kc = 0; kc < 7; ++kc) {
    floatx4 sv[2][4];
#pragma unroll
    for (int t = 0; t < 2; ++t) {
      const int kt = kc * 2 + t;
      const bool valid = (kt < 13);
      short8v bk0, bk1;
      if (valid) {
        const int kpl = kt * 16 + lq;
        bk0 = Kl[kpl * 8 + (lg ^ (kpl & 7))];
        bk1 = Kl[kpl * 8 + ((4 + lg) ^ (kpl & 7))];
      }
      float pm[4];
#pragma unroll
      for (int r = 0; r < 4; ++r)
        pm[r] = valid ? padf[kt * 16 + lg * 4 + r] : 1.f;
#pragma unroll
      for (int i = 0; i < 4; ++i) {
        const int mt = i * 4 + w;
        floatx4 S = {0.f, 0.f, 0.f, 0.f};
        if (valid && mt <= 12) {
          S = __builtin_amdgcn_mfma_f32_16x16x32_bf16(bk0, qf[i][0], S, 0, 0, 0);
          S = __builtin_amdgcn_mfma_f32_16x16x32_bf16(bk1, qf[i][1], S, 0, 0, 0);
        }
        const int qrow = mt * 16 + lq;
#pragma unroll
        for (int r = 0; r < 4; ++r) {
          const int kp = kt * 16 + lg * 4 + r;
          bool masked = (!valid) || (mt > 12) || (pm[r] != 0.f);
          if (CAUSAL) masked = masked || (kp > qrow);
          sv[t][i][r] = masked ? -3e38f : S[r] * 0.125f;
        }
      }
    }

    bool trig = false;
#pragma unroll
    for (int t = 0; t < 2; ++t)
#pragma unroll
      for (int i = 0; i < 4; ++i)
#pragma unroll
        for (int r = 0; r < 4; ++r)
          trig = trig || (sv[t][i][r] > m_[i] + 8.f);
    if (__any(trig)) {
#pragma unroll
      for (int i = 0; i < 4; ++i) {
        float tm = -3e38f;
#pragma unroll
        for (int t = 0; t < 2; ++t)
#pragma unroll
          for (int r = 0; r < 4; ++r) tm = fmaxf(tm, sv[t][i][r]);
        tm = fmaxf(tm, __shfl_xor(tm, 16, 64));
        tm = fmaxf(tm, __shfl_xor(tm, 32, 64));
        const float mn = fmaxf(m_[i], tm);
        const float sc = __expf(m_[i] - mn);
        rsP[i] *= sc;
#pragma unroll
        for (int r = 0; r < 4; ++r) {
          const float scq = __shfl(sc, lg * 4 + r, 64);
#pragma unroll
          for (int dt = 0; dt < 4; ++dt) Of[i][dt][r] *= scq;
        }
        m_[i] = mn;
      }
    }

#pragma unroll
    for (int t = 0; t < 2; ++t)
#pragma unroll
      for (int i = 0; i < 4; ++i) {
        const int mt = i * 4 + w;
        if (mt > 12) continue;
        float p[4];
#pragma unroll
        for (int r = 0; r < 4; ++r) {
          const float s = sv[t][i][r];
          p[r] = (s < -1e37f) ? 0.f : __expf(s - m_[i]);
          rsP[i] += p[r];
        }
        uint2 pk;
        pk.x = (uint)f2bf(p[0]) | ((uint)f2bf(p[1]) << 16);
        pk.y = (uint)f2bf(p[2]) | ((uint)f2bf(p[3]) << 16);
        *(uint2*)&Pw[(w * 4 + i) * 640 + lq * 40 + t * 16 + lg * 4] = pk;
      }

    short8v vb[4];
#pragma unroll
    for (int dt = 0; dt < 4; ++dt) {
      const int d  = dt * 16 + lq;
      const int sk = kc * 4 + lg;
      vb[dt] = ((const short8v*)Vt)[d * 32 + (sk ^ (d & 7))];
    }
#pragma unroll
    for (int i = 0; i < 4; ++i) {
      const int mt = i * 4 + w;
      if (mt > 12) continue;
      const short8v pa = *(const short8v*)&Pw[(w * 4 + i) * 640 + lq * 40 + lg * 8];
#pragma unroll
      for (int dt = 0; dt < 4; ++dt)
        Of[i][dt] = __builtin_amdgcn_mfma_f32_16x16x32_bf16(pa, vb[dt], Of[i][dt], 0, 0, 0);
    }
  }

#pragma unroll
  for (int i = 0; i < 4; ++i) {
    const int mt = i * 4 + w;
    if (mt > 12) continue;
    float rowsum = rsP[i];
    rowsum += __shfl_xor(rowsum, 16, 64);
    rowsum += __shfl_xor(rowsum, 32, 64);
#pragma unroll
    for (int r = 0; r < 4; ++r) {
      const float rs = __shfl(rowsum, lg * 4 + r, 64);
      const int qrow = mt * 16 + lg * 4 + r;
      if (qrow >= SQl) continue;
      const float linv = 1.0f / rs;
      ushort* op = out + ((size_t)(b * SQl + qrow)) * DD + h * HDm;
#pragma unroll
      for (int dt = 0; dt < 4; ++dt)
        op[dt * 16 + lq] = f2bf(Of[i][dt][r] * linv);
    }
  }
}

// ---------------- driver ----------------
extern "C" void kernel_launch(void* const* d_in, const int* in_sizes, int n_in,
                              void* d_out, int out_size, void* d_ws, size_t ws_size,
                              hipStream_t stream) {
  (void)in_sizes; (void)n_in; (void)out_size; (void)ws_size;

  const int*   qids  = (const int*)  d_in[0];
  const float* key   = (const float*)d_in[1];
  const float* value = (const float*)d_in[2];
  const float* emb   = (const float*)d_in[3];
  const float* ln1_g = (const float*)d_in[4];
  const float* ln2_g = (const float*)d_in[5];
  const float* ln3_g = (const float*)d_in[6];
  const float* ln1_b = (const float*)d_in[7];
  const float* ln2_b = (const float*)d_in[8];
  const float* ln3_b = (const float*)d_in[9];
  const float* Wq_s  = (const float*)d_in[10];
  const float* Wk_s  = (const float*)d_in[11];
  const float* Wv_s  = (const float*)d_in[12];
  const float* Wo_s  = (const float*)d_in[13];
  const float* Wq_c  = (const float*)d_in[14];
  const float* Wk_c  = (const float*)d_in[15];
  const float* Wv_c  = (const float*)d_in[16];
  const float* Wo_c  = (const float*)d_in[17];
  const float* bq_s  = (const float*)d_in[18];
  const float* bk_s  = (const float*)d_in[19];
  const float* bv_s  = (const float*)d_in[20];
  const float* bq_c  = (const float*)d_in[21];
  const float* bk_c  = (const float*)d_in[22];
  const float* bv_c  = (const float*)d_in[23];
  const float* W1    = (const float*)d_in[24];
  const float* bf1   = (const float*)d_in[25];
  const float* W2    = (const float*)d_in[26];
  const float* bf2   = (const float*)d_in[27];
  const float* lnf_g = (const float*)d_in[28];
  const float* lnf_b = (const float*)d_in[29];

  const size_t NTOK = (size_t)BB * SQl * DD;     // 6,553,600
  const size_t MEL  = (size_t)DD * DD;
  char* w = (char*)d_ws;
  ushort* o    = (ushort*)w; w += NTOK * 2;      // bf16 residual stream
  ushort* t0b  = (ushort*)w; w += NTOK * 2;
  ushort* qkv  = (ushort*)w; w += (size_t)BB * SQl * 3 * DD * 2;
  ushort* kc   = (ushort*)w; w += (size_t)BB * SQl * 6 * DD * 2;
  ushort* vc   = (ushort*)w; w += (size_t)BB * SQl * 6 * DD * 2;
  ushort* kb   = (ushort*)w; w += NTOK * 2;
  ushort* vb   = (ushort*)w; w += NTOK * 2;
  ushort* fbb  = (ushort*)w; w += (size_t)BB * SQl * FFD * 2;
  ushort* wt   = (ushort*)w; w += 48 * MEL * 2;
  ushort* wt1  = (ushort*)w; w += (size_t)NL * DD * FFD * 2;
  ushort* wt2  = (ushort*)w; w += (size_t)NL * FFD * DD * 2;

  const int M = BB * SQl;                        // 6400
  const BiasP nob = {{nullptr, nullptr, nullptr, nullptr, nullptr, nullptr}};

  embed_pe_kernel<<<(int)(NTOK / 256), 256, 0, stream>>>(qids, emb, o);
  cvt_bf16_kernel<<<(int)(NTOK / 8 + 255) / 256, 256, 0, stream>>>(key,   kb, (int)(NTOK / 8));
  cvt_bf16_kernel<<<(int)(NTOK / 8 + 255) / 256, 256, 0, stream>>>(value, vb, (int)(NTOK / 8));

  P8 p8 = {{Wq_s, Wk_s, Wv_s, Wo_s, Wq_c, Wk_c, Wv_c, Wo_c}};
  transpose48_kernel<<<dim3(32, 32, 48), 256, 0, stream>>>(p8, wt);
  transposeW_kernel<<<dim3(FFD / 32, DD / 32, NL), 256, 0, stream>>>(W1, wt1, DD, FFD);
  transposeW_kernel<<<dim3(DD / 32, FFD / 32, NL), 256, 0, stream>>>(W2, wt2, FFD, DD);

  ushort* wtQKV = wt;                 // [l][3M]
  ushort* wtOs  = wt + 18 * MEL;      // [l][1M]
  ushort* wtQc  = wt + 24 * MEL;
  ushort* wtKc  = wt + 30 * MEL;
  ushort* wtVc  = wt + 36 * MEL;
  ushort* wtOc  = wt + 42 * MEL;

  // cross-attention K/V for ALL layers (layer-invariant A): two N=6144 GEMMs
  {
    BiasP bk6, bv6;
#pragma unroll
    for (int l = 0; l < NL; ++l) { bk6.p[l] = bk_c + l * DD; bv6.p[l] = bv_c + l * DD; }
    launch_g(kb, wtKc, bk6, kc, M, 6 * DD, DD, 6 * DD, 3, stream);
    launch_g(vb, wtVc, bv6, vc, M, 6 * DD, DD, 6 * DD, 3, stream);
  }

  for (int l = 0; l < NL; ++l) {
    // ---- self-attention ----
    ln4_kernel<1><<<M / 4, 256, 0, stream>>>(o, ln1_g + l * DD, ln1_b + l * DD, nullptr, t0b);
    BiasP bqkv = {{bq_s + l * DD, bk_s + l * DD, bv_s + l * DD, nullptr, nullptr, nullptr}};
    launch_g(t0b, wtQKV + l * 3 * MEL, bqkv, qkv, M, 3 * DD, DD, 3 * DD, 3, stream);
    attn_mfma_kernel<1><<<BB * NH, 256, 0, stream>>>(qkv, 3 * DD, qkv + DD, 3 * DD,
                                                     qkv + 2 * DD, 3 * DD, qids, t0b);
    launch_g(t0b, wtOs + l * MEL, nob, o, M, DD, DD, DD, 1, stream);

    // ---- cross-attention ----
    ln4_kernel<1><<<M / 4, 256, 0, stream>>>(o, ln2_g + l * DD, ln2_b + l * DD, nullptr, t0b);
    BiasP bqc = {{bq_c + l * DD, nullptr, nullptr, nullptr, nullptr, nullptr}};
    launch_g(t0b, wtQc + l * MEL, bqc, qkv, M, DD, DD, 3 * DD, 3, stream);
    attn_mfma_kernel<0><<<BB * NH, 256, 0, stream>>>(qkv, 3 * DD, kc + l * DD, 6 * DD,
                                                     vc + l * DD, 6 * DD, nullptr, t0b);
    launch_g(t0b, wtOc + l * MEL, nob, o, M, DD, DD, DD, 1, stream);

    // ---- feed-forward ----
    ln4_kernel<1><<<M / 4, 256, 0, stream>>>(o, ln3_g + l * DD, ln3_b + l * DD, nullptr, t0b);
    BiasP bf1p = {{bf1 + l * FFD, bf1 + l * FFD + DD, nullptr, nullptr, nullptr, nullptr}};
    launch_g(t0b, wt1 + (size_t)l * DD * FFD, bf1p, fbb, M, FFD, DD, FFD, 2, stream);
    BiasP bf2p = {{bf2 + l * DD, nullptr, nullptr, nullptr, nullptr, nullptr}};
    launch_g(fbb, wt2 + (size_t)l * FFD * DD, bf2p, o, M, DD, FFD, DD, 1, stream);
  }

  ln4_kernel<0><<<M / 4, 256, 0, stream>>>(o, lnf_g, lnf_b, (float*)d_out, nullptr);
}